// Round 1
// baseline (241.901 us; speedup 1.0000x reference)
//
#include <hip/hip_runtime.h>
#include <hip/hip_bf16.h>
#include <stdint.h>

#define BATCH 16
#define CIN   256
#define HH    112
#define WW    112
#define GROUPS 2
#define CG    128   // cin per group
#define COG   128   // cout per group
#define RH    4     // output rows per block (main kernel)
#define CK    32    // cin chunk staged per K-iter
#define NCHUNK (CG/CK)

typedef __bf16 bf16x8 __attribute__((ext_vector_type(8)));
typedef float  f32x4  __attribute__((ext_vector_type(4)));

// ---- workspace layout ----
#define WB_BYTES   (GROUPS*3*3*COG*CG*2)        // 589824
#define ZBUF_OFF   WB_BYTES
#define ZBUF_BYTES 8192
#define XB_OFF     (ZBUF_OFF + ZBUF_BYTES)      // 598016
#define XB_BYTES   ((size_t)BATCH*HH*WW*CIN*2)  // 102760448
#define WS_NEED    ((size_t)XB_OFF + XB_BYTES)  // 103358464

__device__ inline void load_lds16(const void* g, void* l) {
    __builtin_amdgcn_global_load_lds(
        (const __attribute__((address_space(1))) void*)g,
        (__attribute__((address_space(3))) void*)l, 16, 0, 0);
}

// ---- pre-pass 1: weights OIHW fp32 -> [g][kh][kw][cout][cin] bf16 ----
__global__ __launch_bounds__(256) void k_wcvt(const float* __restrict__ w,
                                              ushort* __restrict__ wb) {
    int i = blockIdx.x * 256 + threadIdx.x;   // 294912 total
    int ci = i & 127;
    int t  = i >> 7;
    int co = t & 127;
    t >>= 7;                                  // t = g*9 + kh*3 + kw
    int kw = t % 3; t /= 3;
    int kh = t % 3;
    int g  = t / 3;
    int src = (((g*COG + co)*CG + ci)*3 + kh)*3 + kw;
    __hip_bfloat16 v = __float2bfloat16(w[src]);
    wb[i] = *reinterpret_cast<ushort*>(&v);
}

// ---- pre-pass 2: x NCHW fp32 -> NHWC bf16 (LDS transpose) ----
#define XPAD 113
__global__ __launch_bounds__(256) void k_xcvt(const float* __restrict__ x,
                                              ushort* __restrict__ xb) {
    __shared__ float tile[64 * XPAD];
    int bid = blockIdx.x;            // 16*112*4 = 7168
    int cc  = bid & 3;               // chunk of 64 channels
    int h   = (bid >> 2) % HH;
    int b   = bid / (4 * HH);
    int tid = threadIdx.x;

    const float* src = x + ((size_t)(b*CIN + cc*64) * HH + h) * WW;
    for (int tt = tid; tt < 64*28; tt += 256) {
        int c = tt / 28, v = tt % 28;
        float4 f = *reinterpret_cast<const float4*>(src + (size_t)c*HH*WW + v*4);
        float* d = &tile[c*XPAD + v*4];
        d[0]=f.x; d[1]=f.y; d[2]=f.z; d[3]=f.w;
    }
    __syncthreads();

    if (tid < 224) {
        int w = tid >> 1, half = tid & 1;
        ushort o[32];
#pragma unroll
        for (int j = 0; j < 32; ++j) {
            __hip_bfloat16 v = __float2bfloat16(tile[(half*32 + j)*XPAD + w]);
            o[j] = *reinterpret_cast<ushort*>(&v);
        }
        ushort* dst = xb + (((size_t)(b*HH + h)*WW + w)*CIN + cc*64 + half*32);
        const uint4* o4 = reinterpret_cast<const uint4*>(o);
        uint4* d4 = reinterpret_cast<uint4*>(dst);
        d4[0]=o4[0]; d4[1]=o4[1]; d4[2]=o4[2]; d4[3]=o4[3];
    }
}

// ---- weight tile stage: one global_load_lds per wave (8 insts total) ----
__device__ inline void stage_w(const ushort* __restrict__ wb, ushort* dstbuf,
                               int g, int kkw, int chunk, int wave, int lane) {
    int co = wave*16 + (lane >> 2);
    int c  = (lane & 3) * 8;
    const ushort* src = wb + (((size_t)(g*9 + kkw)*COG + co)*CG + chunk*CK + c);
    load_lds16(src, dstbuf + wave*16*CK);
}

// ---- main kernel: implicit-GEMM grouped conv, bf16 MFMA ----
__global__ __launch_bounds__(512, 2) void k_conv(const ushort* __restrict__ xb,
                                                 const ushort* __restrict__ wb,
                                                 const float* __restrict__ bias,
                                                 float* __restrict__ out,
                                                 const ushort* __restrict__ zbuf) {
    __shared__ __align__(16) ushort xs[6*114*CK];        // 43776 B
    __shared__ __align__(16) ushort wsb[2][COG*CK];      // 16384 B

    int bid = blockIdx.x;          // 896 = 2g * 16b * 28q
    int g   = bid / 448;
    int r   = bid % 448;
    int b   = r / 28;
    int q   = r % 28;
    int oh0 = q * RH;

    int tid  = threadIdx.x;
    int wave = tid >> 6;
    int lane = tid & 63;
    int wm   = wave >> 2;          // cout half (0..1)
    int wr   = wave & 3;           // output row within quad (0..3)
    int l15  = lane & 15;
    int lk   = lane >> 4;

    // zero the pad columns (w=0 and w=113) once; stages never touch them
    if (tid < 384) {
        int rr = tid / 64, wcol = (tid >> 5) & 1, c = tid & 31;
        xs[(rr*114 + wcol*113)*CK + c] = 0;
    }

    f32x4 acc[4][7];
#pragma unroll
    for (int m = 0; m < 4; ++m)
#pragma unroll
        for (int n = 0; n < 7; ++n) acc[m][n] = f32x4{0.f,0.f,0.f,0.f};

    for (int chunk = 0; chunk < NCHUNK; ++chunk) {
        // stage 6 halo rows of x for this cin-chunk: 42 wave-tasks
        for (int t = wave; t < 42; t += 8) {
            int rr = t / 7, ii = t % 7;
            int h    = oh0 - 1 + rr;
            int w_in = ii*16 + (lane >> 2);
            int c    = (lane & 3) * 8;
            const ushort* src;
            if (h >= 0 && h < HH)
                src = xb + (((size_t)(b*HH + h)*WW + w_in)*CIN + g*CG + chunk*CK + c);
            else
                src = zbuf + lane*8;
            load_lds16(src, &xs[(rr*114 + 1 + ii*16)*CK]);
        }
        stage_w(wb, wsb[0], g, 0, chunk, wave, lane);
        __syncthreads();   // drains vmcnt -> stages visible

        for (int kkw = 0; kkw < 9; ++kkw) {
            int cur = kkw & 1;
            if (kkw < 8) stage_w(wb, wsb[cur ^ 1], g, kkw + 1, chunk, wave, lane);
            int kh = kkw / 3, kw = kkw - kh*3;

            // B fragments: x row (wr+kh), 7 n-frags, k = cin (contiguous 16B)
            bf16x8 bfr[7];
            const ushort* xrow = &xs[((wr + kh)*114)*CK];
#pragma unroll
            for (int n = 0; n < 7; ++n) {
                int w = n*16 + l15 + kw;
                bfr[n] = *reinterpret_cast<const bf16x8*>(&xrow[w*CK + lk*8]);
            }
            const ushort* wrow = wsb[cur];
#pragma unroll
            for (int m = 0; m < 4; ++m) {
                int co = wm*64 + m*16 + l15;
                bf16x8 afr = *reinterpret_cast<const bf16x8*>(&wrow[co*CK + lk*8]);
#pragma unroll
                for (int n = 0; n < 7; ++n)
                    acc[m][n] = __builtin_amdgcn_mfma_f32_16x16x32_bf16(
                        afr, bfr[n], acc[m][n], 0, 0, 0);
            }
            __syncthreads();
        }
    }

    // epilogue: bias + store (D: row=(lane>>4)*4+j -> cout, col=lane&15 -> ow)
    int oh = oh0 + wr;
#pragma unroll
    for (int m = 0; m < 4; ++m) {
        int cob = g*CG + wm*64 + m*16 + lk*4;
#pragma unroll
        for (int j = 0; j < 4; ++j) {
            int co = cob + j;
            float bv = bias[co];
            float* orow = out + (((size_t)(b*CIN + co)*HH + oh)*WW);
#pragma unroll
            for (int n = 0; n < 7; ++n)
                orow[n*16 + l15] = acc[m][n][j] + bv;
        }
    }
}

// ---- fallback: direct fp32 conv (used only if ws is too small) ----
__global__ __launch_bounds__(128) void k_direct(const float* __restrict__ x,
                                                const float* __restrict__ w,
                                                const float* __restrict__ bias,
                                                float* __restrict__ out) {
    int bid = blockIdx.x;          // B*Cout*H
    int oh  = bid % HH;
    int t   = bid / HH;
    int co  = t % CIN;
    int b   = t / CIN;
    int ow  = threadIdx.x;
    if (ow >= WW) return;
    int g = co / COG;
    float s = bias[co];
    const float* wp = w + (size_t)co*CG*9;
    const float* xp = x + ((size_t)b*CIN + g*CG)*HH*WW;
    for (int ci = 0; ci < CG; ++ci) {
        const float* xr = xp + (size_t)ci*HH*WW;
        const float* wr_ = wp + ci*9;
#pragma unroll
        for (int kh = 0; kh < 3; ++kh) {
            int ih = oh + kh - 1;
            if (ih < 0 || ih >= HH) continue;
#pragma unroll
            for (int kw = 0; kw < 3; ++kw) {
                int iw = ow + kw - 1;
                if (iw < 0 || iw >= WW) continue;
                s += xr[ih*WW + iw] * wr_[kh*3 + kw];
            }
        }
    }
    out[(((size_t)b*CIN + co)*HH + oh)*WW + ow] = s;
}

extern "C" void kernel_launch(void* const* d_in, const int* in_sizes, int n_in,
                              void* d_out, int out_size, void* d_ws, size_t ws_size,
                              hipStream_t stream) {
    const float* x    = (const float*)d_in[0];
    const float* w    = (const float*)d_in[1];
    const float* bias = (const float*)d_in[2];
    float* out        = (float*)d_out;

    if (ws_size >= WS_NEED) {
        ushort* wb   = (ushort*)d_ws;
        ushort* zb   = (ushort*)((char*)d_ws + ZBUF_OFF);
        ushort* xbuf = (ushort*)((char*)d_ws + XB_OFF);
        hipMemsetAsync(zb, 0, ZBUF_BYTES, stream);
        k_wcvt<<<1152, 256, 0, stream>>>(w, wb);
        k_xcvt<<<BATCH*HH*4, 256, 0, stream>>>(x, xbuf);
        k_conv<<<896, 512, 0, stream>>>(xbuf, wb, bias, out, zb);
    } else {
        k_direct<<<BATCH*CIN*HH, 128, 0, stream>>>(x, w, bias, out);
    }
}

// Round 2
// 236.747 us; speedup vs baseline: 1.0218x; 1.0218x over previous
//
#include <hip/hip_runtime.h>
#include <hip/hip_bf16.h>
#include <stdint.h>

#define BATCH 16
#define CIN   256
#define HH    112
#define WW    112
#define GROUPS 2
#define CG    128   // cin per group
#define COG   128   // cout per group
#define RH    4     // output rows per block (main kernel)
#define CK    32    // cin chunk staged per K-iter
#define NCHUNK (CG/CK)

typedef __bf16 bf16x8 __attribute__((ext_vector_type(8)));
typedef float  f32x4  __attribute__((ext_vector_type(4)));

// ---- workspace layout ----
#define WB_BYTES   (GROUPS*3*3*COG*CG*2)        // 589824
#define ZBUF_OFF   WB_BYTES
#define ZBUF_BYTES 8192
#define XB_OFF     (ZBUF_OFF + ZBUF_BYTES)      // 598016
#define XB_BYTES   ((size_t)BATCH*HH*WW*CIN*2)  // 102760448
#define WS_NEED    ((size_t)XB_OFF + XB_BYTES)  // 103358464

__device__ inline void load_lds16(const void* g, void* l) {
    __builtin_amdgcn_global_load_lds(
        (const __attribute__((address_space(1))) void*)g,
        (__attribute__((address_space(3))) void*)l, 16, 0, 0);
}

// ---- pre-pass 1: weights OIHW fp32 -> [g][kh][kw][cout][cin] bf16 ----
__global__ __launch_bounds__(256) void k_wcvt(const float* __restrict__ w,
                                              ushort* __restrict__ wb) {
    int i = blockIdx.x * 256 + threadIdx.x;   // 294912 total
    int ci = i & 127;
    int t  = i >> 7;
    int co = t & 127;
    t >>= 7;                                  // t = g*9 + kh*3 + kw
    int kw = t % 3; t /= 3;
    int kh = t % 3;
    int g  = t / 3;
    int src = (((g*COG + co)*CG + ci)*3 + kh)*3 + kw;
    __hip_bfloat16 v = __float2bfloat16(w[src]);
    wb[i] = *reinterpret_cast<ushort*>(&v);
}

// ---- pre-pass 2: x NCHW fp32 -> NHWC bf16 (LDS transpose) ----
#define XPAD 113
__global__ __launch_bounds__(256) void k_xcvt(const float* __restrict__ x,
                                              ushort* __restrict__ xb) {
    __shared__ float tile[64 * XPAD];
    int bid = blockIdx.x;            // 16*112*4 = 7168
    int cc  = bid & 3;               // chunk of 64 channels
    int h   = (bid >> 2) % HH;
    int b   = bid / (4 * HH);
    int tid = threadIdx.x;

    const float* src = x + ((size_t)(b*CIN + cc*64) * HH + h) * WW;
    for (int tt = tid; tt < 64*28; tt += 256) {
        int c = tt / 28, v = tt % 28;
        float4 f = *reinterpret_cast<const float4*>(src + (size_t)c*HH*WW + v*4);
        float* d = &tile[c*XPAD + v*4];
        d[0]=f.x; d[1]=f.y; d[2]=f.z; d[3]=f.w;
    }
    __syncthreads();

    if (tid < 224) {
        int w = tid >> 1, half = tid & 1;
        ushort o[32];
#pragma unroll
        for (int j = 0; j < 32; ++j) {
            __hip_bfloat16 v = __float2bfloat16(tile[(half*32 + j)*XPAD + w]);
            o[j] = *reinterpret_cast<ushort*>(&v);
        }
        ushort* dst = xb + (((size_t)(b*HH + h)*WW + w)*CIN + cc*64 + half*32);
        const uint4* o4 = reinterpret_cast<const uint4*>(o);
        uint4* d4 = reinterpret_cast<uint4*>(dst);
        d4[0]=o4[0]; d4[1]=o4[1]; d4[2]=o4[2]; d4[3]=o4[3];
    }
}

// ---- weight tile stage (swizzled source: slot t = (lane&3)^((lane>>3)&3)) ----
__device__ inline void stage_w(const ushort* __restrict__ wb, ushort* dstbuf,
                               int g, int kkw, int chunk, int wave, int lane) {
    int co = wave*16 + (lane >> 2);
    int t  = (lane & 3) ^ ((lane >> 3) & 3);
    const ushort* src = wb + (((size_t)(g*9 + kkw)*COG + co)*CG + chunk*CK + t*8);
    load_lds16(src, dstbuf + wave*16*CK);
}

// ---- main kernel: implicit-GEMM grouped conv, bf16 MFMA, swizzled LDS ----
//
// LDS swizzle: each 64B row (32 bf16 channels) is split into 4 slots of 16B.
// Slot s of LDS row R holds channel-slot t = s ^ ((R>>1)&3). Readers XOR the
// same term; global_load_lds writes linearly so the SOURCE channel offset is
// pre-swizzled per lane. Spreads 16 consecutive rows over all 8 bank-groups
// (2 lanes/group = conflict-free), vs 8-way conflicted unswizzled.
__global__ __launch_bounds__(512, 2) void k_conv(const ushort* __restrict__ xb,
                                                 const ushort* __restrict__ wb,
                                                 const float* __restrict__ bias,
                                                 float* __restrict__ out,
                                                 const ushort* __restrict__ zbuf) {
    __shared__ __align__(16) ushort xs[6*114*CK];        // 43776 B
    __shared__ __align__(16) ushort wsb[2][COG*CK];      // 16384 B

    int bid = blockIdx.x;          // 896 = 2g * 16b * 28q
    int g   = bid / 448;
    int r   = bid % 448;
    int b   = r / 28;
    int q   = r % 28;
    int oh0 = q * RH;

    int tid  = threadIdx.x;
    int wave = tid >> 6;
    int lane = tid & 63;
    int wm   = wave >> 2;          // cout half (0..1)
    int wr   = wave & 3;           // output row within quad (0..3)
    int l15  = lane & 15;
    int lk   = lane >> 4;

    // zero the pad columns (w=0 and w=113) once; stages never touch them
    if (tid < 384) {
        int rr = tid / 64, wcol = (tid >> 5) & 1, c = tid & 31;
        xs[(rr*114 + wcol*113)*CK + c] = 0;
    }

    // per-thread constant swizzle terms
    int sA = lk ^ ((l15 >> 1) & 3);                  // weight-read slot
    int qv = lane >> 2;                              // staging row-within-16

    f32x4 acc[4][7];
#pragma unroll
    for (int m = 0; m < 4; ++m)
#pragma unroll
        for (int n = 0; n < 7; ++n) acc[m][n] = f32x4{0.f,0.f,0.f,0.f};

    for (int chunk = 0; chunk < NCHUNK; ++chunk) {
        // stage 6 halo rows of x for this cin-chunk: 42 wave-tasks
        for (int t = wave; t < 42; t += 8) {
            int rr = t / 7, ii = t % 7;
            int h    = oh0 - 1 + rr;
            int w_in = ii*16 + qv;
            // LDS row R = rr*114 + 1 + ii*16 + qv; (R>>1)&3 = ((2rr+1+qv)>>1)&3
            int ts   = (lane & 3) ^ (((2*rr + 1 + qv) >> 1) & 3);
            const ushort* src;
            if (h >= 0 && h < HH)
                src = xb + (((size_t)(b*HH + h)*WW + w_in)*CIN + g*CG + chunk*CK + ts*8);
            else
                src = zbuf + lane*8;
            load_lds16(src, &xs[(rr*114 + 1 + ii*16)*CK]);
        }
        stage_w(wb, wsb[0], g, 0, chunk, wave, lane);
        __syncthreads();   // drains vmcnt -> stages visible

        for (int kkw = 0; kkw < 9; ++kkw) {
            int cur = kkw & 1;
            if (kkw < 8) stage_w(wb, wsb[cur ^ 1], g, kkw + 1, chunk, wave, lane);
            int kh = kkw / 3, kw = kkw - kh*3;

            // B fragments: x row (wr+kh), 7 n-frags, k = cin (contiguous 16B)
            // LDS row R = (wr+kh)*114 + n*16 + l15 + kw; swizzle term is
            // n-independent: (R>>1)&3 = ((2*(wr+kh) + l15 + kw)>>1)&3
            int sB = lk ^ (((2*(wr + kh) + l15 + kw) >> 1) & 3);
            const ushort* bbase = &xs[((wr + kh)*114 + l15 + kw)*CK + sB*8];
            bf16x8 bfr[7];
#pragma unroll
            for (int n = 0; n < 7; ++n)
                bfr[n] = *reinterpret_cast<const bf16x8*>(bbase + n*16*CK);

            const ushort* wrow = wsb[cur];
            const ushort* abase = &wrow[(wm*64 + l15)*CK + sA*8];
#pragma unroll
            for (int m = 0; m < 4; ++m) {
                bf16x8 afr = *reinterpret_cast<const bf16x8*>(abase + m*16*CK);
#pragma unroll
                for (int n = 0; n < 7; ++n)
                    acc[m][n] = __builtin_amdgcn_mfma_f32_16x16x32_bf16(
                        afr, bfr[n], acc[m][n], 0, 0, 0);
            }
            __syncthreads();
        }
    }

    // epilogue: bias + store (D: row=(lane>>4)*4+j -> cout, col=lane&15 -> ow)
    int oh = oh0 + wr;
#pragma unroll
    for (int m = 0; m < 4; ++m) {
        int cob = g*CG + wm*64 + m*16 + lk*4;
#pragma unroll
        for (int j = 0; j < 4; ++j) {
            int co = cob + j;
            float bv = bias[co];
            float* orow = out + (((size_t)(b*CIN + co)*HH + oh)*WW);
#pragma unroll
            for (int n = 0; n < 7; ++n)
                orow[n*16 + l15] = acc[m][n][j] + bv;
        }
    }
}

// ---- fallback: direct fp32 conv (used only if ws is too small) ----
__global__ __launch_bounds__(128) void k_direct(const float* __restrict__ x,
                                                const float* __restrict__ w,
                                                const float* __restrict__ bias,
                                                float* __restrict__ out) {
    int bid = blockIdx.x;          // B*Cout*H
    int oh  = bid % HH;
    int t   = bid / HH;
    int co  = t % CIN;
    int b   = t / CIN;
    int ow  = threadIdx.x;
    if (ow >= WW) return;
    int g = co / COG;
    float s = bias[co];
    const float* wp = w + (size_t)co*CG*9;
    const float* xp = x + ((size_t)b*CIN + g*CG)*HH*WW;
    for (int ci = 0; ci < CG; ++ci) {
        const float* xr = xp + (size_t)ci*HH*WW;
        const float* wr_ = wp + ci*9;
#pragma unroll
        for (int kh = 0; kh < 3; ++kh) {
            int ih = oh + kh - 1;
            if (ih < 0 || ih >= HH) continue;
#pragma unroll
            for (int kw = 0; kw < 3; ++kw) {
                int iw = ow + kw - 1;
                if (iw < 0 || iw >= WW) continue;
                s += xr[ih*WW + iw] * wr_[kh*3 + kw];
            }
        }
    }
    out[(((size_t)b*CIN + co)*HH + oh)*WW + ow] = s;
}

extern "C" void kernel_launch(void* const* d_in, const int* in_sizes, int n_in,
                              void* d_out, int out_size, void* d_ws, size_t ws_size,
                              hipStream_t stream) {
    const float* x    = (const float*)d_in[0];
    const float* w    = (const float*)d_in[1];
    const float* bias = (const float*)d_in[2];
    float* out        = (float*)d_out;

    if (ws_size >= WS_NEED) {
        ushort* wb   = (ushort*)d_ws;
        ushort* zb   = (ushort*)((char*)d_ws + ZBUF_OFF);
        ushort* xbuf = (ushort*)((char*)d_ws + XB_OFF);
        hipMemsetAsync(zb, 0, ZBUF_BYTES, stream);
        k_wcvt<<<1152, 256, 0, stream>>>(w, wb);
        k_xcvt<<<BATCH*HH*4, 256, 0, stream>>>(x, xbuf);
        k_conv<<<896, 512, 0, stream>>>(xbuf, wb, bias, out, zb);
    } else {
        k_direct<<<BATCH*CIN*HH, 128, 0, stream>>>(x, w, bias, out);
    }
}

// Round 3
// 225.086 us; speedup vs baseline: 1.0747x; 1.0518x over previous
//
#include <hip/hip_runtime.h>
#include <hip/hip_bf16.h>
#include <stdint.h>

#define BATCH 16
#define CIN   256
#define HH    112
#define WW    112
#define GROUPS 2
#define CG    128   // cin per group
#define COG   128   // cout per group
#define RH    4     // output rows per block (main kernel)
#define CK    32    // cin chunk staged per K-iter
#define NCHUNK (CG/CK)

typedef __bf16 bf16x8 __attribute__((ext_vector_type(8)));
typedef float  f32x4  __attribute__((ext_vector_type(4)));

// ---- workspace layout ----
#define WB_BYTES   (GROUPS*3*3*COG*CG*2)        // 589824
#define ZBUF_OFF   WB_BYTES
#define ZBUF_BYTES 8192
#define XB_OFF     (ZBUF_OFF + ZBUF_BYTES)      // 598016
#define XB_BYTES   ((size_t)BATCH*HH*WW*CIN*2)  // 102760448
#define WS_NEED    ((size_t)XB_OFF + XB_BYTES)  // 103358464

__device__ inline void load_lds16(const void* g, void* l) {
    __builtin_amdgcn_global_load_lds(
        (const __attribute__((address_space(1))) void*)g,
        (__attribute__((address_space(3))) void*)l, 16, 0, 0);
}

// ---- pre-pass 1: weights OIHW fp32 -> [g][kh][kw][cout][cin] bf16 ----
__global__ __launch_bounds__(256) void k_wcvt(const float* __restrict__ w,
                                              ushort* __restrict__ wb) {
    int i = blockIdx.x * 256 + threadIdx.x;   // 294912 total
    int ci = i & 127;
    int t  = i >> 7;
    int co = t & 127;
    t >>= 7;                                  // t = g*9 + kh*3 + kw
    int kw = t % 3; t /= 3;
    int kh = t % 3;
    int g  = t / 3;
    int src = (((g*COG + co)*CG + ci)*3 + kh)*3 + kw;
    __hip_bfloat16 v = __float2bfloat16(w[src]);
    wb[i] = *reinterpret_cast<ushort*>(&v);
}

// ---- pre-pass 2: x NCHW fp32 -> NHWC bf16 (LDS transpose) ----
#define XPAD 113
__global__ __launch_bounds__(256) void k_xcvt(const float* __restrict__ x,
                                              ushort* __restrict__ xb) {
    __shared__ float tile[64 * XPAD];
    int bid = blockIdx.x;            // 16*112*4 = 7168
    int cc  = bid & 3;               // chunk of 64 channels
    int h   = (bid >> 2) % HH;
    int b   = bid / (4 * HH);
    int tid = threadIdx.x;

    const float* src = x + ((size_t)(b*CIN + cc*64) * HH + h) * WW;
    for (int tt = tid; tt < 64*28; tt += 256) {
        int c = tt / 28, v = tt % 28;
        float4 f = *reinterpret_cast<const float4*>(src + (size_t)c*HH*WW + v*4);
        float* d = &tile[c*XPAD + v*4];
        d[0]=f.x; d[1]=f.y; d[2]=f.z; d[3]=f.w;
    }
    __syncthreads();

    if (tid < 224) {
        int w = tid >> 1, half = tid & 1;
        ushort o[32];
#pragma unroll
        for (int j = 0; j < 32; ++j) {
            __hip_bfloat16 v = __float2bfloat16(tile[(half*32 + j)*XPAD + w]);
            o[j] = *reinterpret_cast<ushort*>(&v);
        }
        ushort* dst = xb + (((size_t)(b*HH + h)*WW + w)*CIN + cc*64 + half*32);
        const uint4* o4 = reinterpret_cast<const uint4*>(o);
        uint4* d4 = reinterpret_cast<uint4*>(dst);
        d4[0]=o4[0]; d4[1]=o4[1]; d4[2]=o4[2]; d4[3]=o4[3];
    }
}

// ---- stage all 9 weight taps of one cin-chunk (swizzled source) ----
__device__ inline void stage_w_all(const ushort* __restrict__ wb, ushort* wsb,
                                   int g, int chunk, int wave, int lane) {
    int co = wave*16 + (lane >> 2);
    int t  = (lane & 3) ^ ((lane >> 3) & 3);
#pragma unroll
    for (int tap = 0; tap < 9; ++tap) {
        const ushort* src = wb + (((size_t)(g*9 + tap)*COG + co)*CG + chunk*CK + t*8);
        load_lds16(src, wsb + (tap*COG + wave*16)*CK);
    }
}

// ---- stage 6 halo x rows of one cin-chunk (swizzled source) ----
__device__ inline void stage_x(const ushort* __restrict__ xb, ushort* dst,
                               const ushort* __restrict__ zbuf,
                               int b, int g, int oh0, int chunk, int wave, int lane) {
    int qv = lane >> 2;
    for (int t = wave; t < 42; t += 8) {
        int rr = t / 7, ii = t % 7;
        int h    = oh0 - 1 + rr;
        int w_in = ii*16 + qv;
        // LDS row R = rr*114 + 1 + ii*16 + qv; (R>>1)&3 = ((2rr+1+qv)>>1)&3
        int ts   = (lane & 3) ^ (((2*rr + 1 + qv) >> 1) & 3);
        const ushort* src = (h >= 0 && h < HH)
            ? xb + (((size_t)(b*HH + h)*WW + w_in)*CIN + g*CG + chunk*CK + ts*8)
            : zbuf + lane*8;
        load_lds16(src, dst + (rr*114 + 1 + ii*16)*CK);
    }
}

// ---- main kernel: implicit-GEMM grouped conv, bf16 MFMA ----
// Restructure vs r1: all 9 taps staged per chunk -> the 9-phase MFMA loop is
// barrier-free (252 MFMAs/wave between barriers, was 28). x double-buffered:
// chunk c+1's global_load_lds issued before chunk c's compute; end-of-chunk
// barrier is raw s_barrier + lgkmcnt(0) only (x prefetch stays in flight);
// the full-drain __syncthreads comes only after the (L2-hot) w stage.
__global__ __launch_bounds__(512, 2) void k_conv(const ushort* __restrict__ xb,
                                                 const ushort* __restrict__ wb,
                                                 const float* __restrict__ bias,
                                                 float* __restrict__ out,
                                                 const ushort* __restrict__ zbuf) {
    __shared__ __align__(16) ushort xs[2][6*114*CK];     // 2 x 43776 B
    __shared__ __align__(16) ushort wsb[9*COG*CK];       // 73728 B  (total 161280)

    int bid = blockIdx.x;          // 896 = 2g * 16b * 28q
    int g   = bid / 448;
    int r   = bid % 448;
    int b   = r / 28;
    int q   = r % 28;
    int oh0 = q * RH;

    int tid  = threadIdx.x;
    int wave = tid >> 6;
    int lane = tid & 63;
    int wm   = wave >> 2;          // cout half (0..1)
    int wr   = wave & 3;           // output row within quad (0..3)
    int l15  = lane & 15;
    int lk   = lane >> 4;

    // zero the pad columns (w=0 and w=113) of BOTH x buffers once
    for (int t = tid; t < 768; t += 512) {
        int buf = t / 384, r2 = t % 384;
        int rr = r2 / 64, wcol = (r2 >> 5) & 1, c = r2 & 31;
        xs[buf][(rr*114 + wcol*113)*CK + c] = 0;
    }

    int sA = lk ^ ((l15 >> 1) & 3);                  // weight-read slot

    f32x4 acc[4][7];
#pragma unroll
    for (int m = 0; m < 4; ++m)
#pragma unroll
        for (int n = 0; n < 7; ++n) acc[m][n] = f32x4{0.f,0.f,0.f,0.f};

    // prologue: stage chunk 0 fully, full drain
    stage_x(xb, xs[0], zbuf, b, g, oh0, 0, wave, lane);
    stage_w_all(wb, wsb, g, 0, wave, lane);
    __syncthreads();

#pragma unroll 1
    for (int c = 0; c < NCHUNK; ++c) {
        const ushort* xcur = xs[c & 1];
        if (c + 1 < NCHUNK)
            stage_x(xb, xs[(c + 1) & 1], zbuf, b, g, oh0, c + 1, wave, lane);

        // 9 tap-phases, no barriers: all operands resident in LDS
#pragma unroll
        for (int kkw = 0; kkw < 9; ++kkw) {
            const int kh = kkw / 3, kw = kkw - kh*3;
            int sB = lk ^ (((2*(wr + kh) + l15 + kw) >> 1) & 3);
            const ushort* bbase = &xcur[((wr + kh)*114 + l15 + kw)*CK + sB*8];
            bf16x8 bfr[7];
#pragma unroll
            for (int n = 0; n < 7; ++n)
                bfr[n] = *reinterpret_cast<const bf16x8*>(bbase + n*16*CK);

            const ushort* abase = &wsb[(kkw*COG + wm*64 + l15)*CK + sA*8];
#pragma unroll
            for (int m = 0; m < 4; ++m) {
                bf16x8 afr = *reinterpret_cast<const bf16x8*>(abase + m*16*CK);
#pragma unroll
                for (int n = 0; n < 7; ++n)
                    acc[m][n] = __builtin_amdgcn_mfma_f32_16x16x32_bf16(
                        afr, bfr[n], acc[m][n], 0, 0, 0);
            }
        }

        // barrier #1: waves done READING xs[c&1] + wsb. lgkm-only drain —
        // keep the x(c+1) global_load_lds prefetch in flight (T4).
        __builtin_amdgcn_sched_barrier(0);
        asm volatile("s_waitcnt lgkmcnt(0)" ::: "memory");
        __builtin_amdgcn_s_barrier();

        if (c + 1 < NCHUNK)
            stage_w_all(wb, wsb, g, c + 1, wave, lane);

        // barrier #2: full drain (w stage + the long-overlapped x prefetch)
        __syncthreads();
    }

    // epilogue: bias + store (D: row=(lane>>4)*4+j -> cout, col=lane&15 -> ow)
    int oh = oh0 + wr;
#pragma unroll
    for (int m = 0; m < 4; ++m) {
        int cob = g*CG + wm*64 + m*16 + lk*4;
#pragma unroll
        for (int j = 0; j < 4; ++j) {
            int co = cob + j;
            float bv = bias[co];
            float* orow = out + (((size_t)(b*CIN + co)*HH + oh)*WW);
#pragma unroll
            for (int n = 0; n < 7; ++n)
                orow[n*16 + l15] = acc[m][n][j] + bv;
        }
    }
}

// ---- fallback: direct fp32 conv (used only if ws is too small) ----
__global__ __launch_bounds__(128) void k_direct(const float* __restrict__ x,
                                                const float* __restrict__ w,
                                                const float* __restrict__ bias,
                                                float* __restrict__ out) {
    int bid = blockIdx.x;          // B*Cout*H
    int oh  = bid % HH;
    int t   = bid / HH;
    int co  = t % CIN;
    int b   = t / CIN;
    int ow  = threadIdx.x;
    if (ow >= WW) return;
    int g = co / COG;
    float s = bias[co];
    const float* wp = w + (size_t)co*CG*9;
    const float* xp = x + ((size_t)b*CIN + g*CG)*HH*WW;
    for (int ci = 0; ci < CG; ++ci) {
        const float* xr = xp + (size_t)ci*HH*WW;
        const float* wr_ = wp + ci*9;
#pragma unroll
        for (int kh = 0; kh < 3; ++kh) {
            int ih = oh + kh - 1;
            if (ih < 0 || ih >= HH) continue;
#pragma unroll
            for (int kw = 0; kw < 3; ++kw) {
                int iw = ow + kw - 1;
                if (iw < 0 || iw >= WW) continue;
                s += xr[ih*WW + iw] * wr_[kh*3 + kw];
            }
        }
    }
    out[(((size_t)b*CIN + co)*HH + oh)*WW + ow] = s;
}

extern "C" void kernel_launch(void* const* d_in, const int* in_sizes, int n_in,
                              void* d_out, int out_size, void* d_ws, size_t ws_size,
                              hipStream_t stream) {
    const float* x    = (const float*)d_in[0];
    const float* w    = (const float*)d_in[1];
    const float* bias = (const float*)d_in[2];
    float* out        = (float*)d_out;

    if (ws_size >= WS_NEED) {
        ushort* wb   = (ushort*)d_ws;
        ushort* zb   = (ushort*)((char*)d_ws + ZBUF_OFF);
        ushort* xbuf = (ushort*)((char*)d_ws + XB_OFF);
        hipMemsetAsync(zb, 0, ZBUF_BYTES, stream);
        k_wcvt<<<1152, 256, 0, stream>>>(w, wb);
        k_xcvt<<<BATCH*HH*4, 256, 0, stream>>>(x, xbuf);
        k_conv<<<896, 512, 0, stream>>>(xbuf, wb, bias, out, zb);
    } else {
        k_direct<<<BATCH*CIN*HH, 128, 0, stream>>>(x, w, bias, out);
    }
}